// Round 6
// baseline (257.731 us; speedup 1.0000x reference)
//
#include <hip/hip_runtime.h>
#include <hip/hip_bf16.h>
#include <stdint.h>

// ---------------------------------------------------------------------------
// E=64 H=64 PRE1=512 BNK=1024 S=256 P=16 B=4096. Attention branch dead
// (softmax over size-1 axis == 1). Decomposition (rel is rank-2):
//   Z1[s,i,j,k] = rx*MX[k] + ry*MY[k] + HH[16s+j][k];  Y1 = relu(Z1)
//   out = maxpool_j relu(bn2(Y1 @ Wp2))
// v5: amortize A-construction over 4x more N. WG = (scene, N-quarter),
//     512 thr = 8 waves; wave = 2 rowtiles x 16 ntiles, acc[2][16] (128 regs).
//     Per ks: 32 VALU construction vs 32 MFMA -> MFMA-bound. Construction
//     redundancy 16x -> 4x. B-frags in 4 chunks of 4 w/ lookahead (~200 live
//     regs, no spill under __launch_bounds__(512,2) = 256-VGPR budget).
// ---------------------------------------------------------------------------

typedef __bf16 bf16x8 __attribute__((ext_vector_type(8)));
typedef __bf16 bf16x2 __attribute__((ext_vector_type(2)));
typedef float  f32x4  __attribute__((ext_vector_type(4)));
typedef float  f32x2  __attribute__((ext_vector_type(2)));

// workspace layout (bytes)
#define BP2_OFF 0                         // packed Wp2 bf16: 64nt*16kb*64l*16B = 1 MB
#define HH_OFF  (1u<<20)                  // HH bf16 [4096][512] = 4 MB
#define MX_OFF  (HH_OFF + (4u<<20))       // 512 f32
#define MY_OFF  (MX_OFF + 2048)           // 512 f32
#define CB_OFF  (MY_OFF + 2048)           // 512 f32
#define SH_OFF  (CB_OFF + 2048)           // 512 f32 (0.05*a1)
#define A2_OFF  (SH_OFF + 2048)           // 1024 f32
#define C2_OFF  (A2_OFF + 4096)           // 1024 f32

// LDS layout (bytes)
#define HH_LDS 0        // f32 [16][512], row stride 2048, swizzle ^((row&7)<<5)
#define RX_LDS 32768    // f32 [256]
#define RY_LDS 33792    // f32 [256]
#define MX_LDS 34816    // f32 [512]
#define MY_LDS 36864    // f32 [512]
#define PF_LDS 38912    // f32 [32]
#define LDS_SZ 39040

__device__ __forceinline__ unsigned short f2bf(float f) {
    union { float f; unsigned u; } c; c.f = f;
    unsigned u = c.u;
    return (unsigned short)((u + 0x7fffu + ((u >> 16) & 1u)) >> 16);
}
__device__ __forceinline__ float bfbits2f(unsigned hi) {
    union { unsigned u; float f; } c; c.u = hi; return c.f;
}
__device__ __forceinline__ unsigned pk_bf16(float a, float b) {
#if __has_builtin(__builtin_amdgcn_cvt_pk_bf16_f32)
    bf16x2 p = __builtin_amdgcn_cvt_pk_bf16_f32(a, b);
    union { bf16x2 v; unsigned u; } c; c.v = p; return c.u;
#else
    return (unsigned)f2bf(a) | ((unsigned)f2bf(b) << 16);
#endif
}

// ---------------------------------------------------------------------------
// prep1: pack Wp2 into MFMA B-frag order + fold all BN/bias/0.05 constants.
// B-frag (16x16x32): lane l holds B[k=kb*32+(l>>4)*8+j][n=nt*16+(l&15)],
// packed at ((nt*16+kb)*64+l)*16 bytes.
// ---------------------------------------------------------------------------
__global__ void prep1_kernel(
    const float* __restrict__ Wsp,  const float* __restrict__ bsp,
    const float* __restrict__ Wp1,  const float* __restrict__ bp1,
    const float* __restrict__ gp1,  const float* __restrict__ btp1,
    const float* __restrict__ mp1,  const float* __restrict__ vp1,
    const float* __restrict__ Wp2,  const float* __restrict__ bp2,
    const float* __restrict__ gp2,  const float* __restrict__ btp2,
    const float* __restrict__ mp2,  const float* __restrict__ vp2,
    unsigned char* __restrict__ ws)
{
    int t = blockIdx.x * 256 + threadIdx.x;
    if (t < 65536) {
        int nt = t >> 10, kb = (t >> 6) & 15, l = t & 63;
        int n  = nt * 16 + (l & 15);
        int k0 = kb * 32 + (l >> 4) * 8;
        unsigned w0, w1, w2, w3;
        w0 = f2bf(Wp2[(k0+0)*1024+n]) | ((unsigned)f2bf(Wp2[(k0+1)*1024+n]) << 16);
        w1 = f2bf(Wp2[(k0+2)*1024+n]) | ((unsigned)f2bf(Wp2[(k0+3)*1024+n]) << 16);
        w2 = f2bf(Wp2[(k0+4)*1024+n]) | ((unsigned)f2bf(Wp2[(k0+5)*1024+n]) << 16);
        w3 = f2bf(Wp2[(k0+6)*1024+n]) | ((unsigned)f2bf(Wp2[(k0+7)*1024+n]) << 16);
        uint4 v; v.x = w0; v.y = w1; v.z = w2; v.w = w3;
        ((uint4*)(ws + BP2_OFF))[t] = v;
    } else if (t < 65536 + 512) {
        int k = t - 65536;
        float a1 = gp1[k] * rsqrtf(vp1[k] + 1e-5f);
        float mx = 0.f, my = 0.f, cb = 0.f;
        for (int e = 0; e < 64; ++e) {
            float wv = Wp1[e * 512 + k];
            mx = fmaf(Wsp[e],      wv, mx);
            my = fmaf(Wsp[64 + e], wv, my);
            cb = fmaf(bsp[e],      wv, cb);
        }
        ((float*)(ws + MX_OFF))[k] = 0.05f * a1 * mx;
        ((float*)(ws + MY_OFF))[k] = 0.05f * a1 * my;
        ((float*)(ws + CB_OFF))[k] = 0.05f * a1 * cb + (bp1[k] - mp1[k]) * a1 + btp1[k];
        ((float*)(ws + SH_OFF))[k] = 0.05f * a1;
    } else if (t < 65536 + 512 + 1024) {
        int n = t - 66048;
        float a = gp2[n] * rsqrtf(vp2[n] + 1e-5f);
        ((float*)(ws + A2_OFF))[n] = a;
        ((float*)(ws + C2_OFF))[n] = btp2[n] + (bp2[n] - mp2[n]) * a;
    }
}

// ---------------------------------------------------------------------------
// prep_hh: HH[r][k] = 0.05*a1[k]*sum_q h[r][q]*Wp1[64+q][k] + CB[k], bf16.
// ---------------------------------------------------------------------------
__global__ __launch_bounds__(256) void prep_hh_kernel(
    const float* __restrict__ hst, const float* __restrict__ Wp1,
    unsigned char* __restrict__ ws)
{
    __shared__ float hl[1024];              // 16 rows x 64
    int r0 = blockIdx.x * 16;
    int tid = threadIdx.x;
    ((float4*)hl)[tid] = ((const float4*)(hst + r0 * 64))[tid];
    __syncthreads();
    const float* SH = (const float*)(ws + SH_OFF);
    const float* CB = (const float*)(ws + CB_OFF);
    unsigned short* HH = (unsigned short*)(ws + HH_OFF);
    #pragma unroll
    for (int kk = 0; kk < 2; ++kk) {
        int k = tid + kk * 256;
        float sh = SH[k], cb = CB[k];
        float acc[16];
        #pragma unroll
        for (int j = 0; j < 16; ++j) acc[j] = 0.f;
        for (int q = 0; q < 64; ++q) {
            float wv = Wp1[(64 + q) * 512 + k];
            #pragma unroll
            for (int j = 0; j < 16; ++j) acc[j] = fmaf(hl[j * 64 + q], wv, acc[j]);
        }
        #pragma unroll
        for (int j = 0; j < 16; ++j)
            HH[(r0 + j) * 512 + k] = f2bf(fmaf(acc[j], sh, cb));
    }
}

// ---------------------------------------------------------------------------
// mm2 v5: WG = (scene s, N-quarter ntq). 512 thr = 8 waves.
// Wave w: rowtiles i = {2w, 2w+1} (disjoint), ntiles ntq*16..+15 (shared
// across waves -> L1 broadcast). acc[2][16] = 128 VGPRs, single K pass.
// A-frag on the fly: lane (jl,quad) holds y[j=jl][k=ks*32+quad*8+t],
// y = relu(rx*MX + ry*MY + HH[j]) via packed f32 (v_pk_fma_f32).
// B-frags in 4 chunks of 4 with one-chunk lookahead.
// C/D: lane holds D[row=quad*4+reg][col=jl]; D-rows = j -> maxpool is
// 4-reg max + 2 shfl_xor.
// ---------------------------------------------------------------------------
__global__ __launch_bounds__(512, 2) void mm2_kernel(
    const float* __restrict__ epos,
    const unsigned char* __restrict__ ws,
    float* __restrict__ out)
{
    __shared__ unsigned char smem[LDS_SZ];
    float* RELX = (float*)(smem + RX_LDS);
    float* RELY = (float*)(smem + RY_LDS);
    float* posf = (float*)(smem + PF_LDS);

    const int s   = blockIdx.x >> 2;     // 256 scenes
    const int ntq = blockIdx.x & 3;      // 4 N-quarters (16 ntiles each)
    const int tid = threadIdx.x;
    const int w    = tid >> 6;           // 0..7
    const int l    = tid & 63;
    const int quad = l >> 4;
    const int jl   = l & 15;

    // ---- stage posf, MX/MY, HH ----
    if (tid < 32) posf[tid] = epos[s * 32 + tid];
    ((float*)(smem + MX_LDS))[tid] = ((const float*)(ws + MX_OFF))[tid];
    ((float*)(smem + MY_LDS))[tid] = ((const float*)(ws + MY_OFF))[tid];
    {
        // HH rows 16s..16s+15: 16 x 512 bf16 = 1024 uint4 -> f32 swizzled
        const uint4* src = (const uint4*)(ws + HH_OFF) + s * 1024;
        #pragma unroll
        for (int it = 0; it < 2; ++it) {
            int c = tid + it * 512;
            int row = c >> 6, p16 = c & 63;
            uint4 d = src[c];
            f32x4 f0, f1;
            f0[0] = bfbits2f(d.x << 16); f0[1] = bfbits2f(d.x & 0xffff0000u);
            f0[2] = bfbits2f(d.y << 16); f0[3] = bfbits2f(d.y & 0xffff0000u);
            f1[0] = bfbits2f(d.z << 16); f1[1] = bfbits2f(d.z & 0xffff0000u);
            f1[2] = bfbits2f(d.w << 16); f1[3] = bfbits2f(d.w & 0xffff0000u);
            int ba = row * 2048 + ((p16 * 32) ^ ((row & 7) << 5));
            *(f32x4*)(smem + HH_LDS + ba)      = f0;
            *(f32x4*)(smem + HH_LDS + ba + 16) = f1;
        }
    }
    __syncthreads();
    if (tid < 256) {
        int i = tid >> 4, j = tid & 15;
        RELX[tid] = posf[j * 2]     - posf[i * 2];
        RELY[tid] = posf[j * 2 + 1] - posf[i * 2 + 1];
    }
    __syncthreads();

    // per-lane rx/ry for this wave's 2 rowtiles (i = 2w+rb, j = jl)
    float rxv[2], ryv[2];
    #pragma unroll
    for (int rb = 0; rb < 2; ++rb) {
        rxv[rb] = RELX[(w * 2 + rb) * 16 + jl];
        ryv[rb] = RELY[(w * 2 + rb) * 16 + jl];
    }

    const f32x4 fzero = {0.f, 0.f, 0.f, 0.f};
    f32x4 acc[2][16];
    #pragma unroll
    for (int rb = 0; rb < 2; ++rb)
        #pragma unroll
        for (int ct = 0; ct < 16; ++ct) acc[rb][ct] = fzero;

    const unsigned char* bks0 = ws + BP2_OFF + ((size_t)ntq << 18);  // ntq*16 nt * 16384 B
    const f32x2 zero2 = {0.f, 0.f};

    #pragma unroll 1
    for (int ks = 0; ks < 16; ++ks) {
        // MX/MY/HH for k = ks*32 + quad*8 .. +8
        int mo = (ks * 32 + quad * 8) * 4;
        f32x4 mx0 = *(const f32x4*)(smem + MX_LDS + mo);
        f32x4 mx1 = *(const f32x4*)(smem + MX_LDS + mo + 16);
        f32x4 my0 = *(const f32x4*)(smem + MY_LDS + mo);
        f32x4 my1 = *(const f32x4*)(smem + MY_LDS + mo + 16);
        int ha = jl * 2048 + ((ks * 128 + quad * 32) ^ ((jl & 7) << 5));
        f32x4 hh0 = *(const f32x4*)(smem + HH_LDS + ha);
        f32x4 hh1 = *(const f32x4*)(smem + HH_LDS + ha + 16);

        f32x2 mxp[4] = { __builtin_shufflevector(mx0, mx0, 0, 1),
                         __builtin_shufflevector(mx0, mx0, 2, 3),
                         __builtin_shufflevector(mx1, mx1, 0, 1),
                         __builtin_shufflevector(mx1, mx1, 2, 3) };
        f32x2 myp[4] = { __builtin_shufflevector(my0, my0, 0, 1),
                         __builtin_shufflevector(my0, my0, 2, 3),
                         __builtin_shufflevector(my1, my1, 0, 1),
                         __builtin_shufflevector(my1, my1, 2, 3) };
        f32x2 hhp[4] = { __builtin_shufflevector(hh0, hh0, 0, 1),
                         __builtin_shufflevector(hh0, hh0, 2, 3),
                         __builtin_shufflevector(hh1, hh1, 0, 1),
                         __builtin_shufflevector(hh1, hh1, 2, 3) };

        // Build A-frags for both rowtiles (the amortized VALU work)
        union { unsigned u[4]; bf16x8 v; } af[2];
        #pragma unroll
        for (int rb = 0; rb < 2; ++rb) {
            f32x2 rx2 = { rxv[rb], rxv[rb] };
            f32x2 ry2 = { ryv[rb], ryv[rb] };
            #pragma unroll
            for (int p = 0; p < 4; ++p) {
                f32x2 t = __builtin_elementwise_fma(ry2, myp[p], hhp[p]);
                t = __builtin_elementwise_fma(rx2, mxp[p], t);
                t = __builtin_elementwise_max(t, zero2);
                af[rb].u[p] = pk_bf16(t[0], t[1]);
            }
        }

        // 16 ntiles in 4 chunks of 4 with one-chunk lookahead
        const unsigned char* bkk = bks0 + ((ks * 64 + l) << 4);
        bf16x8 cur[4], nxt[4];
        #pragma unroll
        for (int ct = 0; ct < 4; ++ct)
            cur[ct] = *(const bf16x8*)(bkk + ct * 16384);
        #pragma unroll
        for (int c = 0; c < 4; ++c) {
            if (c < 3) {
                #pragma unroll
                for (int ct = 0; ct < 4; ++ct)
                    nxt[ct] = *(const bf16x8*)(bkk + ((c + 1) * 4 + ct) * 16384);
            }
            #pragma unroll
            for (int rb = 0; rb < 2; ++rb)
                #pragma unroll
                for (int ct = 0; ct < 4; ++ct)
                    acc[rb][c * 4 + ct] = __builtin_amdgcn_mfma_f32_16x16x32_bf16(
                        af[rb].v, cur[ct], acc[rb][c * 4 + ct], 0, 0, 0);
            if (c < 3) {
                #pragma unroll
                for (int ct = 0; ct < 4; ++ct) cur[ct] = nxt[ct];
            }
        }
    }

    // ---- epilogue: bn2 + relu, maxpool over j, store fp32 ----
    const float* A2 = (const float*)(ws + A2_OFF);
    const float* C2 = (const float*)(ws + C2_OFF);
    #pragma unroll
    for (int ct = 0; ct < 16; ++ct) {
        int col = (ntq * 16 + ct) * 16 + jl;
        float a2 = A2[col], c2 = C2[col];
        #pragma unroll
        for (int rb = 0; rb < 2; ++rb) {
            float v0 = fmaxf(fmaf(acc[rb][ct][0], a2, c2), 0.f);
            float v1 = fmaxf(fmaf(acc[rb][ct][1], a2, c2), 0.f);
            float v2 = fmaxf(fmaf(acc[rb][ct][2], a2, c2), 0.f);
            float v3 = fmaxf(fmaf(acc[rb][ct][3], a2, c2), 0.f);
            float v = fmaxf(fmaxf(v0, v1), fmaxf(v2, v3));
            v = fmaxf(v, __shfl_xor(v, 16, 64));
            v = fmaxf(v, __shfl_xor(v, 32, 64));
            if (l < 16) {
                int orow = s * 16 + w * 2 + rb;
                __builtin_nontemporal_store(v, &out[orow * 1024 + col]);
            }
        }
    }
}

extern "C" void kernel_launch(void* const* d_in, const int* in_sizes, int n_in,
                              void* d_out, int out_size, void* d_ws, size_t ws_size,
                              hipStream_t stream) {
    const float* hst  = (const float*)d_in[0];
    const float* epos = (const float*)d_in[1];
    const float* Wsp  = (const float*)d_in[4];
    const float* bsp  = (const float*)d_in[5];
    const float* Wp1  = (const float*)d_in[20];
    const float* bp1  = (const float*)d_in[21];
    const float* gp1  = (const float*)d_in[22];
    const float* btp1 = (const float*)d_in[23];
    const float* mp1  = (const float*)d_in[24];
    const float* vp1  = (const float*)d_in[25];
    const float* Wp2  = (const float*)d_in[26];
    const float* bp2  = (const float*)d_in[27];
    const float* gp2  = (const float*)d_in[28];
    const float* btp2 = (const float*)d_in[29];
    const float* mp2  = (const float*)d_in[30];
    const float* vp2  = (const float*)d_in[31];
    unsigned char* ws = (unsigned char*)d_ws;
    float* out = (float*)d_out;

    prep1_kernel<<<262, 256, 0, stream>>>(Wsp, bsp, Wp1, bp1, gp1, btp1, mp1, vp1,
                                          Wp2, bp2, gp2, btp2, mp2, vp2, ws);
    prep_hh_kernel<<<256, 256, 0, stream>>>(hst, Wp1, ws);
    // 256 scenes x 4 N-quarters, 512 threads (8 waves)
    mm2_kernel<<<1024, 512, 0, stream>>>(epos, ws, out);
}

// Round 7
// 244.943 us; speedup vs baseline: 1.0522x; 1.0522x over previous
//
#include <hip/hip_runtime.h>
#include <hip/hip_bf16.h>
#include <stdint.h>

// ---------------------------------------------------------------------------
// E=64 H=64 PRE1=512 BNK=1024 S=256 P=16 B=4096. Attention branch dead
// (softmax over size-1 axis == 1). Decomposition (rel is rank-2):
//   Z1[s,i,j,k] = rx*MX[k] + ry*MY[k] + HH[16s+j][k];  Y1 = relu(Z1)
//   out = maxpool_j relu(bn2(Y1 @ Wp2))
// v6: (a) mm2 B-tiles staged via __builtin_amdgcn_global_load_lds (16B) into
//     a double-buffered LDS region -- DMA queue depth is VGPR-free, killing
//     the exposed L2 latency that pinned v5 at 23% MfmaUtil.
//     (b) wave tiling rebalanced to 4i x 8nt (acc[4][8]): B LDS re-reads
//     halve; construction stays below MFMA cost.
//     (c) preps rewritten: Wp2/W1b pack via LDS transpose (coalesced reads),
//     HH computed by a small MFMA kernel, stored f32 (mm2 skips unpack).
// ---------------------------------------------------------------------------

typedef __bf16 bf16x8 __attribute__((ext_vector_type(8)));
typedef __bf16 bf16x2 __attribute__((ext_vector_type(2)));
typedef float  f32x4  __attribute__((ext_vector_type(4)));
typedef float  f32x2  __attribute__((ext_vector_type(2)));

// workspace layout (bytes)
#define BP2_OFF 0u          // packed Wp2: 64nt*16kb*64l*16B = 1 MB
#define BP1_OFF 1048576u    // packed W1b (Wp1 rows 64..127): 32nt*2kb*64l*16B = 64 KB
#define MX_OFF  1114112u    // 512 f32
#define MY_OFF  1116160u
#define CB_OFF  1118208u
#define SH_OFF  1120256u
#define A2_OFF  1122304u    // 1024 f32
#define C2_OFF  1126400u
#define HH_OFF  1130496u    // HH f32 [4096][512] = 8 MB
// total ~9.52 MB

// mm2 LDS layout (bytes)
#define HH_LDS 0            // f32 [16][512], row stride 2048, swizzle ^((row&7)<<5)
#define RX_LDS 32768        // f32 [256]
#define RY_LDS 33792        // f32 [256]
#define MX_LDS 34816        // f32 [512]
#define MY_LDS 36864        // f32 [512]
#define PF_LDS 38912        // f32 [32]
#define BB_LDS 39040        // B double buffer: 2 x 16 KB
#define LDS_SZ 71808

__device__ __forceinline__ unsigned short f2bf(float f) {
    union { float f; unsigned u; } c; c.f = f;
    unsigned u = c.u;
    return (unsigned short)((u + 0x7fffu + ((u >> 16) & 1u)) >> 16);
}
__device__ __forceinline__ unsigned pk_bf16(float a, float b) {
#if __has_builtin(__builtin_amdgcn_cvt_pk_bf16_f32)
    bf16x2 p = __builtin_amdgcn_cvt_pk_bf16_f32(a, b);
    union { bf16x2 v; unsigned u; } c; c.v = p; return c.u;
#else
    return (unsigned)f2bf(a) | ((unsigned)f2bf(b) << 16);
#endif
}

typedef const __attribute__((address_space(1))) unsigned int* gas_t;
typedef __attribute__((address_space(3))) unsigned int* las_t;
__device__ __forceinline__ void dma16(const void* g, void* l) {
    __builtin_amdgcn_global_load_lds((gas_t)g, (las_t)l, 16, 0, 0);
}

// ---------------------------------------------------------------------------
// prep_pack: blocks 0..255 pack Wp2, 256..271 pack W1b (both via LDS
// transpose; all global reads float4-coalesced), 272..273 fold k-consts,
// 274..277 fold A2/C2.
// B-frag (16x16x32): lane l holds B[k=kb*32+(l>>4)*8+j][n=nt*16+(l&15)],
// packed at ((nt*KB+kb)*64+l)*16 bytes.
// ---------------------------------------------------------------------------
__global__ __launch_bounds__(256) void prep_pack_kernel(
    const float* __restrict__ Wsp,  const float* __restrict__ bsp,
    const float* __restrict__ Wp1,  const float* __restrict__ bp1,
    const float* __restrict__ gp1,  const float* __restrict__ btp1,
    const float* __restrict__ mp1,  const float* __restrict__ vp1,
    const float* __restrict__ Wp2,  const float* __restrict__ bp2,
    const float* __restrict__ gp2,  const float* __restrict__ btp2,
    const float* __restrict__ mp2,  const float* __restrict__ vp2,
    unsigned char* __restrict__ ws)
{
    __shared__ float tile[32 * 65];
    const int blk = blockIdx.x, t = threadIdx.x;

    if (blk < 272) {
        const float* src; int ncols, kb, ng, KB; unsigned outoff;
        if (blk < 256) { kb = blk >> 4; ng = blk & 15; src = Wp2; ncols = 1024; KB = 16; outoff = BP2_OFF; }
        else { int b2 = blk - 256; kb = b2 >> 3; ng = b2 & 7; src = Wp1 + 64 * 512; ncols = 512; KB = 2; outoff = BP1_OFF; }
        const int k0 = kb * 32, n0 = ng * 64;
        #pragma unroll
        for (int it = 0; it < 2; ++it) {
            int c = t + it * 256;
            int r = c >> 4, c4 = c & 15;
            float4 v = *(const float4*)(src + (k0 + r) * ncols + n0 + c4 * 4);
            tile[r * 65 + c4 * 4 + 0] = v.x;
            tile[r * 65 + c4 * 4 + 1] = v.y;
            tile[r * 65 + c4 * 4 + 2] = v.z;
            tile[r * 65 + c4 * 4 + 3] = v.w;
        }
        __syncthreads();
        int ntl = t >> 6, l = t & 63;
        int nl = ntl * 16 + (l & 15), kl = (l >> 4) * 8;
        uint4 o;
        o.x = pk_bf16(tile[(kl + 0) * 65 + nl], tile[(kl + 1) * 65 + nl]);
        o.y = pk_bf16(tile[(kl + 2) * 65 + nl], tile[(kl + 3) * 65 + nl]);
        o.z = pk_bf16(tile[(kl + 4) * 65 + nl], tile[(kl + 5) * 65 + nl]);
        o.w = pk_bf16(tile[(kl + 6) * 65 + nl], tile[(kl + 7) * 65 + nl]);
        ((uint4*)(ws + outoff))[((ng * 4 + ntl) * KB + kb) * 64 + l] = o;
    } else if (blk < 274) {
        int k = (blk - 272) * 256 + t;
        float a1 = gp1[k] * rsqrtf(vp1[k] + 1e-5f);
        float mx = 0.f, my = 0.f, cb = 0.f;
        for (int e = 0; e < 64; ++e) {
            float wv = Wp1[e * 512 + k];
            mx = fmaf(Wsp[e],      wv, mx);
            my = fmaf(Wsp[64 + e], wv, my);
            cb = fmaf(bsp[e],      wv, cb);
        }
        ((float*)(ws + MX_OFF))[k] = 0.05f * a1 * mx;
        ((float*)(ws + MY_OFF))[k] = 0.05f * a1 * my;
        ((float*)(ws + CB_OFF))[k] = 0.05f * a1 * cb + (bp1[k] - mp1[k]) * a1 + btp1[k];
        ((float*)(ws + SH_OFF))[k] = 0.05f * a1;
    } else {
        int n = (blk - 274) * 256 + t;
        float a = gp2[n] * rsqrtf(vp2[n] + 1e-5f);
        ((float*)(ws + A2_OFF))[n] = a;
        ((float*)(ws + C2_OFF))[n] = btp2[n] + (bp2[n] - mp2[n]) * a;
    }
}

// ---------------------------------------------------------------------------
// hh_kernel: HH[r][k] = SH[k] * (h @ W1b)[r][k] + CB[k], f32, via MFMA.
// 64 blocks x 256 thr (4 waves); block = 64 h-rows; wave w owns 8 ntiles.
// ---------------------------------------------------------------------------
__global__ __launch_bounds__(256) void hh_kernel(
    const float* __restrict__ hst, const unsigned char* __restrict__ ws)
{
    __shared__ __align__(16) unsigned char hs[64 * 128];  // bf16 [64 rows][64 k], swizzled
    const int t = threadIdx.x, r0 = blockIdx.x * 64;
    #pragma unroll
    for (int it = 0; it < 4; ++it) {
        int c = t + it * 256;
        int row = c >> 4, q4 = c & 15;
        float4 v = *(const float4*)(hst + (r0 + row) * 64 + q4 * 4);
        uint2 p; p.x = pk_bf16(v.x, v.y); p.y = pk_bf16(v.z, v.w);
        int off = (q4 * 8) ^ ((row & 7) << 4);
        *(uint2*)(hs + row * 128 + off) = p;
    }
    __syncthreads();

    const int w = t >> 6, l = t & 63, quad = l >> 4, jl = l & 15;
    const f32x4 fzero = {0.f, 0.f, 0.f, 0.f};
    f32x4 acc[4][8];
    #pragma unroll
    for (int rt = 0; rt < 4; ++rt)
        #pragma unroll
        for (int ct = 0; ct < 8; ++ct) acc[rt][ct] = fzero;

    #pragma unroll
    for (int ks = 0; ks < 2; ++ks) {
        bf16x8 af[4];
        #pragma unroll
        for (int rt = 0; rt < 4; ++rt) {
            int row = rt * 16 + jl;
            int off = (ks * 64 + quad * 16) ^ ((row & 7) << 4);
            af[rt] = *(const bf16x8*)(hs + row * 128 + off);
        }
        #pragma unroll
        for (int ct = 0; ct < 8; ++ct) {
            bf16x8 bfr = *(const bf16x8*)(ws + BP1_OFF + ((((w * 8 + ct) * 2 + ks) * 64 + l) << 4));
            #pragma unroll
            for (int rt = 0; rt < 4; ++rt)
                acc[rt][ct] = __builtin_amdgcn_mfma_f32_16x16x32_bf16(af[rt], bfr, acc[rt][ct], 0, 0, 0);
        }
    }

    const float* SH = (const float*)(ws + SH_OFF);
    const float* CB = (const float*)(ws + CB_OFF);
    float* HHf = (float*)((unsigned char*)ws + HH_OFF);   // ws is const; cast away
    #pragma unroll
    for (int ct = 0; ct < 8; ++ct) {
        int col = (w * 8 + ct) * 16 + jl;
        float sh = SH[col], cb = CB[col];
        #pragma unroll
        for (int rt = 0; rt < 4; ++rt) {
            #pragma unroll
            for (int reg = 0; reg < 4; ++reg) {
                int row = r0 + rt * 16 + quad * 4 + reg;
                HHf[row * 512 + col] = fmaf(acc[rt][ct][reg], sh, cb);
            }
        }
    }
}

// ---------------------------------------------------------------------------
// mm2 v6: WG = (scene s, N-quarter ntq). 512 thr = 8 waves.
// Wave w = (ig = w>>1, ng = w&1): rowtiles i = ig*4..+3, ntiles ng*8..+7
// within the quarter. acc[4][8] = 128 AGPRs. Per ks: B slice (16 nt x 1 KB)
// DMA'd into LDS dbuf by all 8 waves (2 slices each) one iteration ahead;
// barrier per ks drains the in-flight DMA after a full compute phase.
// A-frags built on the fly from HH/MX/MY in LDS (packed f32 math).
// ---------------------------------------------------------------------------
__global__ __launch_bounds__(512, 2) void mm2_kernel(
    const float* __restrict__ epos,
    const unsigned char* __restrict__ ws,
    float* __restrict__ out)
{
    __shared__ __align__(16) unsigned char smem[LDS_SZ];
    float* RELX = (float*)(smem + RX_LDS);
    float* RELY = (float*)(smem + RY_LDS);
    float* posf = (float*)(smem + PF_LDS);

    const int s   = blockIdx.x >> 2;
    const int ntq = blockIdx.x & 3;
    const int tid = threadIdx.x;
    const int w    = tid >> 6;
    const int l    = tid & 63;
    const int quad = l >> 4;
    const int jl   = l & 15;
    const int ig   = w >> 1;
    const int ng   = w & 1;

    const unsigned char* bws = ws + BP2_OFF;

    // ---- issue DMA for ks=0 into buf0 (latency overlaps staging) ----
    {
        const void* g0 = bws + ((((ntq * 16 + 2 * w + 0) * 16 + 0) * 64 + l) << 4);
        const void* g1 = bws + ((((ntq * 16 + 2 * w + 1) * 16 + 0) * 64 + l) << 4);
        dma16(g0, smem + BB_LDS + (2 * w + 0) * 1024);
        dma16(g1, smem + BB_LDS + (2 * w + 1) * 1024);
    }

    // ---- stage posf, MX/MY, HH(f32, swizzled) ----
    if (tid < 32) posf[tid] = epos[s * 32 + tid];
    ((float*)(smem + MX_LDS))[tid] = ((const float*)(ws + MX_OFF))[tid];
    ((float*)(smem + MY_LDS))[tid] = ((const float*)(ws + MY_OFF))[tid];
    {
        const float4* src = (const float4*)(ws + HH_OFF) + s * 2048;  // 16 rows x 128 float4
        #pragma unroll
        for (int it = 0; it < 4; ++it) {
            int c = tid + it * 512;
            int row = c >> 7, p4 = c & 127;
            float4 v = src[c];
            int ba = row * 2048 + ((p4 * 16) ^ ((row & 7) << 5));
            *(float4*)(smem + HH_LDS + ba) = v;
        }
    }
    __syncthreads();   // drains DMA(ks=0) too
    if (tid < 256) {
        int i = tid >> 4, j = tid & 15;
        RELX[tid] = posf[j * 2]     - posf[i * 2];
        RELY[tid] = posf[j * 2 + 1] - posf[i * 2 + 1];
    }
    __syncthreads();

    float rxv[4], ryv[4];
    #pragma unroll
    for (int rb = 0; rb < 4; ++rb) {
        rxv[rb] = RELX[(ig * 4 + rb) * 16 + jl];
        ryv[rb] = RELY[(ig * 4 + rb) * 16 + jl];
    }

    const f32x4 fzero = {0.f, 0.f, 0.f, 0.f};
    f32x4 acc[4][8];
    #pragma unroll
    for (int rb = 0; rb < 4; ++rb)
        #pragma unroll
        for (int ct = 0; ct < 8; ++ct) acc[rb][ct] = fzero;

    const f32x2 zero2 = {0.f, 0.f};

    #pragma unroll 2
    for (int ks = 0; ks < 16; ++ks) {
        // prefetch ks+1 via DMA into the other buffer (after the barrier
        // that guaranteed everyone is done with it)
        if (ks < 15) {
            const void* g0 = bws + ((((ntq * 16 + 2 * w + 0) * 16 + (ks + 1)) * 64 + l) << 4);
            const void* g1 = bws + ((((ntq * 16 + 2 * w + 1) * 16 + (ks + 1)) * 64 + l) << 4);
            unsigned char* d = smem + BB_LDS + ((ks + 1) & 1) * 16384;
            dma16(g0, d + (2 * w + 0) * 1024);
            dma16(g1, d + (2 * w + 1) * 1024);
        }

        // MX/MY/HH fragments for k = ks*32 + quad*8 .. +8
        int mo = (ks * 32 + quad * 8) * 4;
        f32x4 mx0 = *(const f32x4*)(smem + MX_LDS + mo);
        f32x4 mx1 = *(const f32x4*)(smem + MX_LDS + mo + 16);
        f32x4 my0 = *(const f32x4*)(smem + MY_LDS + mo);
        f32x4 my1 = *(const f32x4*)(smem + MY_LDS + mo + 16);
        int ha = jl * 2048 + ((ks * 128 + quad * 32) ^ ((jl & 7) << 5));
        f32x4 hh0 = *(const f32x4*)(smem + HH_LDS + ha);
        f32x4 hh1 = *(const f32x4*)(smem + HH_LDS + ha + 16);

        f32x2 mxp[4] = { __builtin_shufflevector(mx0, mx0, 0, 1),
                         __builtin_shufflevector(mx0, mx0, 2, 3),
                         __builtin_shufflevector(mx1, mx1, 0, 1),
                         __builtin_shufflevector(mx1, mx1, 2, 3) };
        f32x2 myp[4] = { __builtin_shufflevector(my0, my0, 0, 1),
                         __builtin_shufflevector(my0, my0, 2, 3),
                         __builtin_shufflevector(my1, my1, 0, 1),
                         __builtin_shufflevector(my1, my1, 2, 3) };
        f32x2 hhp[4] = { __builtin_shufflevector(hh0, hh0, 0, 1),
                         __builtin_shufflevector(hh0, hh0, 2, 3),
                         __builtin_shufflevector(hh1, hh1, 0, 1),
                         __builtin_shufflevector(hh1, hh1, 2, 3) };

        union { unsigned u[4]; bf16x8 v; } af[4];
        #pragma unroll
        for (int rb = 0; rb < 4; ++rb) {
            f32x2 rx2 = { rxv[rb], rxv[rb] };
            f32x2 ry2 = { ryv[rb], ryv[rb] };
            #pragma unroll
            for (int p = 0; p < 4; ++p) {
                f32x2 tt = __builtin_elementwise_fma(ry2, myp[p], hhp[p]);
                tt = __builtin_elementwise_fma(rx2, mxp[p], tt);
                tt = __builtin_elementwise_max(tt, zero2);
                af[rb].u[p] = pk_bf16(tt[0], tt[1]);
            }
        }

        // B fragments from LDS (current buffer), 8 ntiles for this wave
        const unsigned char* bb = smem + BB_LDS + (ks & 1) * 16384 + (l << 4);
        #pragma unroll
        for (int ct = 0; ct < 8; ++ct) {
            bf16x8 bfr = *(const bf16x8*)(bb + (ng * 8 + ct) * 1024);
            #pragma unroll
            for (int rb = 0; rb < 4; ++rb)
                acc[rb][ct] = __builtin_amdgcn_mfma_f32_16x16x32_bf16(af[rb].v, bfr, acc[rb][ct], 0, 0, 0);
        }

        __syncthreads();   // drains next-ks DMA (had a full compute phase) + protects buffer reuse
    }

    // ---- epilogue: bn2 + relu, maxpool over j (D rows), store fp32 ----
    const float* A2 = (const float*)(ws + A2_OFF);
    const float* C2 = (const float*)(ws + C2_OFF);
    #pragma unroll
    for (int ct = 0; ct < 8; ++ct) {
        int col = (ntq * 16 + ng * 8 + ct) * 16 + jl;
        float a2 = A2[col], c2 = C2[col];
        #pragma unroll
        for (int rb = 0; rb < 4; ++rb) {
            float v0 = fmaxf(fmaf(acc[rb][ct][0], a2, c2), 0.f);
            float v1 = fmaxf(fmaf(acc[rb][ct][1], a2, c2), 0.f);
            float v2 = fmaxf(fmaf(acc[rb][ct][2], a2, c2), 0.f);
            float v3 = fmaxf(fmaf(acc[rb][ct][3], a2, c2), 0.f);
            float v = fmaxf(fmaxf(v0, v1), fmaxf(v2, v3));
            v = fmaxf(v, __shfl_xor(v, 16, 64));
            v = fmaxf(v, __shfl_xor(v, 32, 64));
            if (l < 16) {
                int orow = s * 16 + ig * 4 + rb;
                __builtin_nontemporal_store(v, &out[orow * 1024 + col]);
            }
        }
    }
}

extern "C" void kernel_launch(void* const* d_in, const int* in_sizes, int n_in,
                              void* d_out, int out_size, void* d_ws, size_t ws_size,
                              hipStream_t stream) {
    const float* hst  = (const float*)d_in[0];
    const float* epos = (const float*)d_in[1];
    const float* Wsp  = (const float*)d_in[4];
    const float* bsp  = (const float*)d_in[5];
    const float* Wp1  = (const float*)d_in[20];
    const float* bp1  = (const float*)d_in[21];
    const float* gp1  = (const float*)d_in[22];
    const float* btp1 = (const float*)d_in[23];
    const float* mp1  = (const float*)d_in[24];
    const float* vp1  = (const float*)d_in[25];
    const float* Wp2  = (const float*)d_in[26];
    const float* bp2  = (const float*)d_in[27];
    const float* gp2  = (const float*)d_in[28];
    const float* btp2 = (const float*)d_in[29];
    const float* mp2  = (const float*)d_in[30];
    const float* vp2  = (const float*)d_in[31];
    unsigned char* ws = (unsigned char*)d_ws;
    float* out = (float*)d_out;

    // 256 (Wp2 pack) + 16 (W1b pack) + 2 (k-consts) + 4 (A2/C2) = 278 blocks
    prep_pack_kernel<<<278, 256, 0, stream>>>(Wsp, bsp, Wp1, bp1, gp1, btp1, mp1, vp1,
                                              Wp2, bp2, gp2, btp2, mp2, vp2, ws);
    hh_kernel<<<64, 256, 0, stream>>>(hst, ws);
    // 256 scenes x 4 N-quarters, 512 threads (8 waves)
    mm2_kernel<<<1024, 512, 0, stream>>>(epos, ws, out);
}